// Round 3
// baseline (1932.981 us; speedup 1.0000x reference)
//
#include <hip/hip_runtime.h>
#include <math.h>

// Problem constants (reference: S,B,I,H = 1024,512,5,32; G=4H=128)
#define S_LEN 1024
#define BATCH 512
#define HID   32

#define LOG2E 1.44269504088896340736f

__device__ __forceinline__ float fast_rcp(float x) { return __builtin_amdgcn_rcpf(x); }
__device__ __forceinline__ float fast_exp2(float x) { return __builtin_amdgcn_exp2f(x); }

// LSTM pointwise tail. accA/accB pre-scaled by log2e (accB by 2*log2e on low
// half, where it holds the g-gate). Lane layout:
//   lane l, j=l&31: low half owns rows gA=l (i_j) and gB=l+64 (g_j);
//   high half owns rows gA=l (f_j) and gB=l+64 (o_j).
// One shfl_xor(32) pair gives every lane all 4 gates of unit j.
__device__ __forceinline__ void lstm_tail(float accA, float accB, bool lowHalf,
                                          float c, float& c_out, float& h_out)
{
    float pA = __shfl_xor(accA, 32);
    float pB = __shfl_xor(accB, 32);
    float yi = lowHalf ? accA : pA;
    float yf = lowHalf ? pA : accA;
    float yg = lowHalf ? accB : pB;   // scaled by 2*log2e
    float yo = lowHalf ? pB : accB;
    float gi = fast_rcp(1.0f + fast_exp2(-yi));
    float gf = fast_rcp(1.0f + fast_exp2(-yf));
    float sg = fast_rcp(1.0f + fast_exp2(-yg));
    float go = fast_rcp(1.0f + fast_exp2(-yo));
    float gg = 2.0f * sg - 1.0f;      // tanh(g) = 2*sigma(2g) - 1
    float cn = gf * c + gi * gg;
    float e  = fast_exp2(-2.0f * LOG2E * fabsf(cn));
    float tc = copysignf((1.0f - e) * fast_rcp(1.0f + e), cn);
    c_out = cn;
    h_out = go * tc;                  // redundant in both halves (by design)
}

// Load one 32-float weight row into registers, pre-scaled.
#define LOADROW(dst, base, row, sc)                                            \
    {                                                                          \
        const float4* W_ = reinterpret_cast<const float4*>((base) +            \
                                                    (size_t)(row) * HID);      \
        _Pragma("unroll")                                                      \
        for (int k4 = 0; k4 < 8; ++k4) {                                       \
            float4 v_ = W_[k4];                                                \
            dst[4 * k4 + 0] = v_.x * (sc);                                     \
            dst[4 * k4 + 1] = v_.y * (sc);                                     \
            dst[4 * k4 + 2] = v_.z * (sc);                                     \
            dst[4 * k4 + 3] = v_.w * (sc);                                     \
        }                                                                      \
    }

// Fused 3-layer LSTM: ONE WAVE per batch element, all three layers in-wave.
// Block = 1 wave => ZERO barriers (DS ops are in-order within a wave).
// h hand-off between layers/ticks through a tiny private LDS buffer, read
// back as same-address ds_read_b128 broadcasts (no LDS bank conflicts, no
// readlane SGPR hazards). launch_bounds(64,1) unlocks the 512-VGPR budget so
// the ~340 floats of weights stay register-resident (round-2's 176-VGPR spill
// was the killer).
// Schedule per tick: loopA(h0 dot) -> tail0 -> loopB(h1 dot) -> tail1 ->
// loopC(h2 dot) -> tail2. Each tail's transcendental chain overlaps the next
// loop's independent loads+FMAs; tail0's h0 write is consumed only at the
// START of the next tick (~2/3 tick later).
__global__ __launch_bounds__(64, 1)
void lstm3_fused(const float* __restrict__ x,
                 const float* __restrict__ Wih0, const float* __restrict__ Whh0,
                 const float* __restrict__ bih0, const float* __restrict__ bhh0,
                 const float* __restrict__ Wih1, const float* __restrict__ Whh1,
                 const float* __restrict__ bih1, const float* __restrict__ bhh1,
                 const float* __restrict__ Wih2, const float* __restrict__ Whh2,
                 const float* __restrict__ bih2, const float* __restrict__ bhh2,
                 float* __restrict__ hseq)
{
    const int b = blockIdx.x;
    const int l = threadIdx.x & 63;
    const int j = l & 31;
    const bool lowHalf = (l < 32);
    const int gA = l;
    const int gB = l + 64;
    const float sA = LOG2E;
    const float sB = lowHalf ? (2.0f * LOG2E) : LOG2E;  // g rows get 2*log2e

    // Double-buffered h hand-off: hbuf[parity][layer][unit]
    __shared__ float hbuf[2][3][HID];
    for (int i = threadIdx.x; i < 2 * 3 * HID; i += 64)
        (&hbuf[0][0][0])[i] = 0.0f;
    // single wave: DS in-order, no barrier needed

    // ---- weights to registers (live across all ticks) ----
    float whA0[HID], whB0[HID], whA1[HID], whB1[HID], whA2[HID], whB2[HID];
    float wiA1[HID], wiB1[HID], wiA2[HID], wiB2[HID];
    float wxA[5], wxB[5];

    LOADROW(whA0, Whh0, gA, sA); LOADROW(whB0, Whh0, gB, sB);
    LOADROW(whA1, Whh1, gA, sA); LOADROW(whB1, Whh1, gB, sB);
    LOADROW(whA2, Whh2, gA, sA); LOADROW(whB2, Whh2, gB, sB);
    LOADROW(wiA1, Wih1, gA, sA); LOADROW(wiB1, Wih1, gB, sB);
    LOADROW(wiA2, Wih2, gA, sA); LOADROW(wiB2, Wih2, gB, sB);
#pragma unroll
    for (int k = 0; k < 5; ++k) {
        wxA[k] = Wih0[gA * 5 + k] * sA;
        wxB[k] = Wih0[gB * 5 + k] * sB;
    }
    const float b0A = (bih0[gA] + bhh0[gA]) * sA;
    const float b0B = (bih0[gB] + bhh0[gB]) * sB;
    const float b1A = (bih1[gA] + bhh1[gA]) * sA;
    const float b1B = (bih1[gB] + bhh1[gB]) * sB;
    const float b2A = (bih2[gA] + bhh2[gA]) * sA;
    const float b2B = (bih2[gB] + bhh2[gB]) * sB;

    float c0 = 0.f, c1 = 0.f, c2 = 0.f;

    // x[s=0] prefetch: all lanes same address -> broadcast load
    const float* xb = x + (size_t)b * 5;
    float xv0 = xb[0], xv1 = xb[1], xv2 = xb[2], xv3 = xb[3], xv4 = xb[4];

    for (int t = 0; t < S_LEN + 2; ++t) {
        const int p = t & 1;
        const int pn = p ^ 1;
        const float4* h0p = reinterpret_cast<const float4*>(&hbuf[p][0][0]);
        const float4* h1p = reinterpret_cast<const float4*>(&hbuf[p][1][0]);
        const float4* h2p = reinterpret_cast<const float4*>(&hbuf[p][2][0]);

        // 4-wide partial sums per accumulator (independent FMA chains)
        float a0A[4] = {b0A, 0.f, 0.f, 0.f}, a0B[4] = {b0B, 0.f, 0.f, 0.f};
        float a1A[4] = {b1A, 0.f, 0.f, 0.f}, a1B[4] = {b1B, 0.f, 0.f, 0.f};
        float a2A[4] = {b2A, 0.f, 0.f, 0.f}, a2B[4] = {b2B, 0.f, 0.f, 0.f};

        // layer-0 x input (K=5, values in regs)
        a0A[0] += wxA[0] * xv0; a0B[0] += wxB[0] * xv0;
        a0A[1] += wxA[1] * xv1; a0B[1] += wxB[1] * xv1;
        a0A[2] += wxA[2] * xv2; a0B[2] += wxB[2] * xv2;
        a0A[3] += wxA[3] * xv3; a0B[3] += wxB[3] * xv3;
        a0A[0] += wxA[4] * xv4; a0B[0] += wxB[4] * xv4;

        // prefetch next x (uniform address; latency hidden under this tick)
        if (t + 1 < S_LEN) {
            const float* xn = xb + (size_t)(t + 1) * BATCH * 5;
            xv0 = xn[0]; xv1 = xn[1]; xv2 = xn[2]; xv3 = xn[3]; xv4 = xn[4];
        }

        // ---- loop A: h0(t-1) feeds layer0 recurrent + layer1 input ----
#pragma unroll
        for (int k4 = 0; k4 < HID / 4; ++k4) {
            float4 hv = h0p[k4];
            a0A[0] += whA0[4 * k4 + 0] * hv.x;
            a0A[1] += whA0[4 * k4 + 1] * hv.y;
            a0A[2] += whA0[4 * k4 + 2] * hv.z;
            a0A[3] += whA0[4 * k4 + 3] * hv.w;
            a0B[0] += whB0[4 * k4 + 0] * hv.x;
            a0B[1] += whB0[4 * k4 + 1] * hv.y;
            a0B[2] += whB0[4 * k4 + 2] * hv.z;
            a0B[3] += whB0[4 * k4 + 3] * hv.w;
            a1A[0] += wiA1[4 * k4 + 0] * hv.x;
            a1A[1] += wiA1[4 * k4 + 1] * hv.y;
            a1A[2] += wiA1[4 * k4 + 2] * hv.z;
            a1A[3] += wiA1[4 * k4 + 3] * hv.w;
            a1B[0] += wiB1[4 * k4 + 0] * hv.x;
            a1B[1] += wiB1[4 * k4 + 1] * hv.y;
            a1B[2] += wiB1[4 * k4 + 2] * hv.z;
            a1B[3] += wiB1[4 * k4 + 3] * hv.w;
        }
        // tail 0 (a0 complete); its chain overlaps loop B below
        {
            float acc = (a0A[0] + a0A[1]) + (a0A[2] + a0A[3]);
            float accB = (a0B[0] + a0B[1]) + (a0B[2] + a0B[3]);
            float cn, hn;
            lstm_tail(acc, accB, lowHalf, c0, cn, hn);
            if (t < S_LEN) {
                c0 = cn;
                if (lowHalf) hbuf[pn][0][j] = hn;
            }
        }

        // ---- loop B: h1(t-1) feeds layer1 recurrent + layer2 input ----
#pragma unroll
        for (int k4 = 0; k4 < HID / 4; ++k4) {
            float4 hv = h1p[k4];
            a1A[0] += whA1[4 * k4 + 0] * hv.x;
            a1A[1] += whA1[4 * k4 + 1] * hv.y;
            a1A[2] += whA1[4 * k4 + 2] * hv.z;
            a1A[3] += whA1[4 * k4 + 3] * hv.w;
            a1B[0] += whB1[4 * k4 + 0] * hv.x;
            a1B[1] += whB1[4 * k4 + 1] * hv.y;
            a1B[2] += whB1[4 * k4 + 2] * hv.z;
            a1B[3] += whB1[4 * k4 + 3] * hv.w;
            a2A[0] += wiA2[4 * k4 + 0] * hv.x;
            a2A[1] += wiA2[4 * k4 + 1] * hv.y;
            a2A[2] += wiA2[4 * k4 + 2] * hv.z;
            a2A[3] += wiA2[4 * k4 + 3] * hv.w;
            a2B[0] += wiB2[4 * k4 + 0] * hv.x;
            a2B[1] += wiB2[4 * k4 + 1] * hv.y;
            a2B[2] += wiB2[4 * k4 + 2] * hv.z;
            a2B[3] += wiB2[4 * k4 + 3] * hv.w;
        }
        // tail 1 (a1 complete); chain overlaps loop C
        {
            float acc = (a1A[0] + a1A[1]) + (a1A[2] + a1A[3]);
            float accB = (a1B[0] + a1B[1]) + (a1B[2] + a1B[3]);
            float cn, hn;
            lstm_tail(acc, accB, lowHalf, c1, cn, hn);
            if (t >= 1 && t <= S_LEN) {
                c1 = cn;
                if (lowHalf) hbuf[pn][1][j] = hn;
            }
        }

        // ---- loop C: h2(t-1) feeds layer2 recurrent ----
#pragma unroll
        for (int k4 = 0; k4 < HID / 4; ++k4) {
            float4 hv = h2p[k4];
            a2A[0] += whA2[4 * k4 + 0] * hv.x;
            a2A[1] += whA2[4 * k4 + 1] * hv.y;
            a2A[2] += whA2[4 * k4 + 2] * hv.z;
            a2A[3] += whA2[4 * k4 + 3] * hv.w;
            a2B[0] += whB2[4 * k4 + 0] * hv.x;
            a2B[1] += whB2[4 * k4 + 1] * hv.y;
            a2B[2] += whB2[4 * k4 + 2] * hv.z;
            a2B[3] += whB2[4 * k4 + 3] * hv.w;
        }
        // tail 2; h2 is consumed latest next tick (loop C) -> most slack
        {
            float acc = (a2A[0] + a2A[1]) + (a2A[2] + a2A[3]);
            float accB = (a2B[0] + a2B[1]) + (a2B[2] + a2B[3]);
            float cn, hn;
            lstm_tail(acc, accB, lowHalf, c2, cn, hn);
            if (t >= 2) {
                c2 = cn;
                if (lowHalf) {
                    hbuf[pn][2][j] = hn;
                    hseq[((size_t)(t - 2) * BATCH + b) * HID + j] = hn;
                }
            }
        }
    }
}

// MLP head: per (s,b): y = relu(w3 . (W2 (W1 h + b1) + b2) + b3)
__global__ __launch_bounds__(256)
void mlp_kernel(const float* __restrict__ h, const float* __restrict__ w1,
                const float* __restrict__ b1, const float* __restrict__ w2,
                const float* __restrict__ b2, const float* __restrict__ w3,
                const float* __restrict__ b3, float* __restrict__ out)
{
    __shared__ float W1[HID * HID];
    __shared__ float W2[HID * HID];
    __shared__ float W3[HID];
    __shared__ float B1[HID];
    __shared__ float B2[HID];
    __shared__ float B3s;

    for (int i = threadIdx.x; i < HID * HID; i += blockDim.x) {
        W1[i] = w1[i];
        W2[i] = w2[i];
    }
    if (threadIdx.x < HID) {
        W3[threadIdx.x] = w3[threadIdx.x];
        B1[threadIdx.x] = b1[threadIdx.x];
        B2[threadIdx.x] = b2[threadIdx.x];
    }
    if (threadIdx.x == 0) B3s = b3[0];
    __syncthreads();

    const size_t e = (size_t)blockIdx.x * blockDim.x + threadIdx.x;  // (s*B+b)
    float hv[HID];
    const float4* hp = reinterpret_cast<const float4*>(h + e * HID);
#pragma unroll
    for (int k4 = 0; k4 < HID / 4; ++k4) {
        float4 v = hp[k4];
        hv[4 * k4 + 0] = v.x;
        hv[4 * k4 + 1] = v.y;
        hv[4 * k4 + 2] = v.z;
        hv[4 * k4 + 3] = v.w;
    }

    float y1[HID];
#pragma unroll
    for (int jj = 0; jj < HID; ++jj) {
        float acc = B1[jj];
#pragma unroll
        for (int k = 0; k < HID; ++k) acc += W1[jj * HID + k] * hv[k];
        y1[jj] = acc;
    }
    float y2[HID];
#pragma unroll
    for (int jj = 0; jj < HID; ++jj) {
        float acc = B2[jj];
#pragma unroll
        for (int k = 0; k < HID; ++k) acc += W2[jj * HID + k] * y1[k];
        y2[jj] = acc;
    }
    float acc3 = B3s;
#pragma unroll
    for (int k = 0; k < HID; ++k) acc3 += W3[k] * y2[k];
    out[e] = fmaxf(acc3, 0.0f);
}

extern "C" void kernel_launch(void* const* d_in, const int* in_sizes, int n_in,
                              void* d_out, int out_size, void* d_ws, size_t ws_size,
                              hipStream_t stream)
{
    const float* x    = (const float*)d_in[0];
    const float* Wih0 = (const float*)d_in[1];
    const float* Whh0 = (const float*)d_in[2];
    const float* bih0 = (const float*)d_in[3];
    const float* bhh0 = (const float*)d_in[4];
    const float* Wih1 = (const float*)d_in[5];
    const float* Whh1 = (const float*)d_in[6];
    const float* bih1 = (const float*)d_in[7];
    const float* bhh1 = (const float*)d_in[8];
    const float* Wih2 = (const float*)d_in[9];
    const float* Whh2 = (const float*)d_in[10];
    const float* bih2 = (const float*)d_in[11];
    const float* bhh2 = (const float*)d_in[12];
    const float* w1   = (const float*)d_in[13];
    const float* b1   = (const float*)d_in[14];
    const float* w2   = (const float*)d_in[15];
    const float* b2   = (const float*)d_in[16];
    const float* w3   = (const float*)d_in[17];
    const float* b3   = (const float*)d_in[18];

    // [S, BATCH, HID] fp32 buffer (64 MB) for layer-2 output
    float* hseq = (float*)d_ws;

    lstm3_fused<<<BATCH, 64, 0, stream>>>(x, Wih0, Whh0, bih0, bhh0,
                                          Wih1, Whh1, bih1, bhh1,
                                          Wih2, Whh2, bih2, bhh2, hseq);

    mlp_kernel<<<(S_LEN * BATCH) / 256, 256, 0, stream>>>(hseq, w1, b1, w2, b2, w3, b3,
                                                          (float*)d_out);
}

// Round 4
// 908.588 us; speedup vs baseline: 2.1275x; 2.1275x over previous
//
#include <hip/hip_runtime.h>
#include <math.h>

// Problem constants (reference: S,B,I,H = 1024,512,5,32; G=4H=128)
#define S_LEN 1024
#define BATCH 512
#define HID   32

#define LOG2E 1.44269504088896340736f

__device__ __forceinline__ float fast_rcp(float x) { return __builtin_amdgcn_rcpf(x); }
__device__ __forceinline__ float fast_exp2(float x) { return __builtin_amdgcn_exp2f(x); }

// Tick barrier: make LDS writes visible across waves WITHOUT draining vmcnt.
// __syncthreads() would emit s_waitcnt vmcnt(0) before s_barrier, serializing
// the in-flight hseq global stores into every tick. We only need lgkmcnt.
__device__ __forceinline__ void tick_barrier() {
    asm volatile("s_waitcnt lgkmcnt(0)" ::: "memory");
    __builtin_amdgcn_s_barrier();
    asm volatile("" ::: "memory");   // compiler fence: no LDS op hoisted above
}

// Load one 32-float weight row into registers, pre-scaled.
#define LOADROW(dst, base, row, sc)                                            \
    {                                                                          \
        const float4* W_ = reinterpret_cast<const float4*>((base) +            \
                                                    (size_t)(row) * HID);      \
        _Pragma("unroll")                                                      \
        for (int k4 = 0; k4 < 8; ++k4) {                                       \
            float4 v_ = W_[k4];                                                \
            dst[4 * k4 + 0] = v_.x * (sc);                                     \
            dst[4 * k4 + 1] = v_.y * (sc);                                     \
            dst[4 * k4 + 2] = v_.z * (sc);                                     \
            dst[4 * k4 + 3] = v_.w * (sc);                                     \
        }                                                                      \
    }

// Fused 3-layer LSTM, software-pipelined across waves (round-0 structure).
// Block = 192 threads = 3 waves; wave w = layer w; blockIdx = batch element.
// At tick t, wave w processes step s = t - w; h hand-off via double-buffered
// LDS ring; ONE raw barrier per tick (no vmcnt drain).
// Lane l owns rows gA=l and gB=l+64 (torch gate order i,f,g,o):
//   lanes 0-31 (j=l):    i_j (accA), g_j (accB)
//   lanes 32-63 (j=l-32): f_j (accA), o_j (accB)
// Weights/biases pre-scaled by log2e (g rows by 2*log2e) so all activations
// are the uniform sigma(y)=rcp(1+exp2(-y)); tanh(g)=2*sigma(2g)-1.
// x block-slice staged in LDS once -> zero per-tick global loads.
__global__ __launch_bounds__(192, 2)
void lstm3_fused(const float* __restrict__ x,
                 const float* __restrict__ Wih0, const float* __restrict__ Whh0,
                 const float* __restrict__ bih0, const float* __restrict__ bhh0,
                 const float* __restrict__ Wih1, const float* __restrict__ Whh1,
                 const float* __restrict__ bih1, const float* __restrict__ bhh1,
                 const float* __restrict__ Wih2, const float* __restrict__ Whh2,
                 const float* __restrict__ bih2, const float* __restrict__ bhh2,
                 float* __restrict__ hseq)
{
    const int b = blockIdx.x;
    const int w = threadIdx.x >> 6;   // wave id == layer id, 0..2
    const int l = threadIdx.x & 63;
    const int j = l & 31;
    const bool lowHalf = (l < 32);
    const int gA = l;
    const int gB = l + 64;
    const float sA = LOG2E;
    const float sB = lowHalf ? (2.0f * LOG2E) : LOG2E;  // g rows get 2*log2e

    // x slice for this batch element: xl4[s] = x[s][b][0..3], xl1[s] = x[s][b][4]
    __shared__ float4 xl4[S_LEN];     // 16 KB
    __shared__ float  xl1[S_LEN];     //  4 KB
    // ring[parity][slot][unit]; slot w+1 holds layer w's h. Slot 0 unused.
    __shared__ float ring[2][4][HID];

    for (int i = threadIdx.x; i < 2 * 4 * HID; i += 192)
        (&ring[0][0][0])[i] = 0.0f;
    {
        float* xf = reinterpret_cast<float*>(xl4);
        for (int idx = threadIdx.x; idx < S_LEN * 5; idx += 192) {
            const int s = idx / 5;
            const int c = idx - 5 * s;
            const float v = x[(size_t)s * (BATCH * 5) + b * 5 + c];
            if (c < 4) xf[s * 4 + c] = v;
            else       xl1[s] = v;
        }
    }

    const float* Wih = (w == 0) ? Wih0 : (w == 1) ? Wih1 : Wih2;
    const float* Whh = (w == 0) ? Whh0 : (w == 1) ? Whh1 : Whh2;
    const float* bih = (w == 0) ? bih0 : (w == 1) ? bih1 : bih2;
    const float* bhh = (w == 0) ? bhh0 : (w == 1) ? bhh1 : bhh2;

    // Recurrent weight rows in registers (all waves), pre-scaled
    float whA[HID], whB[HID];
    LOADROW(whA, Whh, gA, sA);
    LOADROW(whB, Whh, gB, sB);
    // Input weight rows: wave 0 has KIN=5, waves 1/2 have KIN=32.
    float wiA[HID], wiB[HID];
    float wxA[5], wxB[5];
    if (w == 0) {
#pragma unroll
        for (int k = 0; k < 5; ++k) {
            wxA[k] = Wih[gA * 5 + k] * sA;
            wxB[k] = Wih[gB * 5 + k] * sB;
        }
    } else {
        LOADROW(wiA, Wih, gA, sA);
        LOADROW(wiB, Wih, gB, sB);
    }
    const float biasA = (bih[gA] + bhh[gA]) * sA;
    const float biasB = (bih[gB] + bhh[gB]) * sB;

    float c = 0.0f;

    __syncthreads();  // staging + ring init visible (one-time full barrier)

    for (int t = 0; t < S_LEN + 2; ++t) {
        const int s = t - w;
        const bool active = (s >= 0) && (s < S_LEN);
        const int p = t & 1;

        // ---- gate matvecs: acc = bias + Whh*h_own + Wih*input ----
        float aA0 = biasA, aA1 = 0.f, aA2 = 0.f, aA3 = 0.f;
        float aB0 = biasB, aB1 = 0.f, aB2 = 0.f, aB3 = 0.f;

        // own h from LDS (written by this wave last tick), broadcast reads
        const float4* hown4 = reinterpret_cast<const float4*>(&ring[p][w + 1][0]);
#pragma unroll
        for (int k4 = 0; k4 < HID / 4; ++k4) {
            float4 hv = hown4[k4];
            aA0 += whA[4 * k4 + 0] * hv.x;
            aA1 += whA[4 * k4 + 1] * hv.y;
            aA2 += whA[4 * k4 + 2] * hv.z;
            aA3 += whA[4 * k4 + 3] * hv.w;
            aB0 += whB[4 * k4 + 0] * hv.x;
            aB1 += whB[4 * k4 + 1] * hv.y;
            aB2 += whB[4 * k4 + 2] * hv.z;
            aB3 += whB[4 * k4 + 3] * hv.w;
        }

        if (w == 0) {
            if (active) {   // wave-uniform branch
                const float4 xv = xl4[s];
                const float  x4 = xl1[s];
                aA0 += wxA[0] * xv.x; aB0 += wxB[0] * xv.x;
                aA1 += wxA[1] * xv.y; aB1 += wxB[1] * xv.y;
                aA2 += wxA[2] * xv.z; aB2 += wxB[2] * xv.z;
                aA3 += wxA[3] * xv.w; aB3 += wxB[3] * xv.w;
                aA0 += wxA[4] * x4;   aB0 += wxB[4] * x4;
            }
        } else {
            // input = previous layer's h from LDS ring
            const float4* hin4 = reinterpret_cast<const float4*>(&ring[p][w][0]);
#pragma unroll
            for (int k4 = 0; k4 < HID / 4; ++k4) {
                float4 hv = hin4[k4];
                aA0 += wiA[4 * k4 + 0] * hv.x;
                aA1 += wiA[4 * k4 + 1] * hv.y;
                aA2 += wiA[4 * k4 + 2] * hv.z;
                aA3 += wiA[4 * k4 + 3] * hv.w;
                aB0 += wiB[4 * k4 + 0] * hv.x;
                aB1 += wiB[4 * k4 + 1] * hv.y;
                aB2 += wiB[4 * k4 + 2] * hv.z;
                aB3 += wiB[4 * k4 + 3] * hv.w;
            }
        }
        const float accA = (aA0 + aA1) + (aA2 + aA3);
        const float accB = (aB0 + aB1) + (aB2 + aB3);

        // ---- exchange halves: both halves get all 4 gates of unit j ----
        const float pA = __shfl_xor(accA, 32);
        const float pB = __shfl_xor(accB, 32);
        const float yi = lowHalf ? accA : pA;
        const float yf = lowHalf ? pA : accA;
        const float yg = lowHalf ? accB : pB;   // scaled by 2*log2e
        const float yo = lowHalf ? pB : accB;

        const float gi = fast_rcp(1.0f + fast_exp2(-yi));
        const float gf = fast_rcp(1.0f + fast_exp2(-yf));
        const float sg = fast_rcp(1.0f + fast_exp2(-yg));
        const float go = fast_rcp(1.0f + fast_exp2(-yo));
        const float gg = 2.0f * sg - 1.0f;      // tanh(g) = 2*sigma(2g) - 1

        const float c_new = gf * c + gi * gg;
        const float e  = fast_exp2(-2.0f * LOG2E * fabsf(c_new));
        const float tc = copysignf((1.0f - e) * fast_rcp(1.0f + e), c_new);
        const float h = go * tc;                // redundant in both halves

        if (active) {
            c = c_new;
            if (lowHalf) {
                ring[p ^ 1][w + 1][j] = h;      // for me + next layer, next tick
                if (w == 2)
                    hseq[((size_t)s * BATCH + b) * HID + j] = h;  // never waited
            }
        }
        tick_barrier();   // lgkmcnt-only: stores stream, no vmcnt drain
    }
}

// MLP head: per (s,b): y = relu(w3 . (W2 (W1 h + b1) + b2) + b3)
__global__ __launch_bounds__(256)
void mlp_kernel(const float* __restrict__ h, const float* __restrict__ w1,
                const float* __restrict__ b1, const float* __restrict__ w2,
                const float* __restrict__ b2, const float* __restrict__ w3,
                const float* __restrict__ b3, float* __restrict__ out)
{
    __shared__ float W1[HID * HID];
    __shared__ float W2[HID * HID];
    __shared__ float W3[HID];
    __shared__ float B1[HID];
    __shared__ float B2[HID];
    __shared__ float B3s;

    for (int i = threadIdx.x; i < HID * HID; i += blockDim.x) {
        W1[i] = w1[i];
        W2[i] = w2[i];
    }
    if (threadIdx.x < HID) {
        W3[threadIdx.x] = w3[threadIdx.x];
        B1[threadIdx.x] = b1[threadIdx.x];
        B2[threadIdx.x] = b2[threadIdx.x];
    }
    if (threadIdx.x == 0) B3s = b3[0];
    __syncthreads();

    const size_t e = (size_t)blockIdx.x * blockDim.x + threadIdx.x;  // (s*B+b)
    float hv[HID];
    const float4* hp = reinterpret_cast<const float4*>(h + e * HID);
#pragma unroll
    for (int k4 = 0; k4 < HID / 4; ++k4) {
        float4 v = hp[k4];
        hv[4 * k4 + 0] = v.x;
        hv[4 * k4 + 1] = v.y;
        hv[4 * k4 + 2] = v.z;
        hv[4 * k4 + 3] = v.w;
    }

    float y1[HID];
#pragma unroll
    for (int jj = 0; jj < HID; ++jj) {
        float acc = B1[jj];
#pragma unroll
        for (int k = 0; k < HID; ++k) acc += W1[jj * HID + k] * hv[k];
        y1[jj] = acc;
    }
    float y2[HID];
#pragma unroll
    for (int jj = 0; jj < HID; ++jj) {
        float acc = B2[jj];
#pragma unroll
        for (int k = 0; k < HID; ++k) acc += W2[jj * HID + k] * y1[k];
        y2[jj] = acc;
    }
    float acc3 = B3s;
#pragma unroll
    for (int k = 0; k < HID; ++k) acc3 += W3[k] * y2[k];
    out[e] = fmaxf(acc3, 0.0f);
}

extern "C" void kernel_launch(void* const* d_in, const int* in_sizes, int n_in,
                              void* d_out, int out_size, void* d_ws, size_t ws_size,
                              hipStream_t stream)
{
    const float* x    = (const float*)d_in[0];
    const float* Wih0 = (const float*)d_in[1];
    const float* Whh0 = (const float*)d_in[2];
    const float* bih0 = (const float*)d_in[3];
    const float* bhh0 = (const float*)d_in[4];
    const float* Wih1 = (const float*)d_in[5];
    const float* Whh1 = (const float*)d_in[6];
    const float* bih1 = (const float*)d_in[7];
    const float* bhh1 = (const float*)d_in[8];
    const float* Wih2 = (const float*)d_in[9];
    const float* Whh2 = (const float*)d_in[10];
    const float* bih2 = (const float*)d_in[11];
    const float* bhh2 = (const float*)d_in[12];
    const float* w1   = (const float*)d_in[13];
    const float* b1   = (const float*)d_in[14];
    const float* w2   = (const float*)d_in[15];
    const float* b2   = (const float*)d_in[16];
    const float* w3   = (const float*)d_in[17];
    const float* b3   = (const float*)d_in[18];

    // [S, BATCH, HID] fp32 buffer (64 MB) for layer-2 output
    float* hseq = (float*)d_ws;

    lstm3_fused<<<BATCH, 192, 0, stream>>>(x, Wih0, Whh0, bih0, bhh0,
                                           Wih1, Whh1, bih1, bhh1,
                                           Wih2, Whh2, bih2, bhh2, hseq);

    mlp_kernel<<<(S_LEN * BATCH) / 256, 256, 0, stream>>>(hseq, w1, b1, w2, b2, w3, b3,
                                                          (float*)d_out);
}

// Round 5
// 884.236 us; speedup vs baseline: 2.1860x; 1.0275x over previous
//
#include <hip/hip_runtime.h>
#include <math.h>

// Problem constants (reference: S,B,I,H = 1024,512,5,32; G=4H=128)
#define S_LEN 1024
#define BATCH 512
#define HID   32

#define LOG2E 1.44269504088896340736f

__device__ __forceinline__ float fast_rcp(float x) { return __builtin_amdgcn_rcpf(x); }
__device__ __forceinline__ float fast_exp2(float x) { return __builtin_amdgcn_exp2f(x); }

// Tick barrier: make LDS writes visible across waves WITHOUT draining vmcnt.
// __syncthreads() would emit s_waitcnt vmcnt(0) before s_barrier, serializing
// in-flight hseq global stores into every tick. We only need lgkmcnt.
__device__ __forceinline__ void tick_barrier() {
    asm volatile("s_waitcnt lgkmcnt(0)" ::: "memory");
    __builtin_amdgcn_s_barrier();
    asm volatile("" ::: "memory");   // compiler fence: no LDS op hoisted above
}

// gfx950 v_permlane32_swap_b32: swaps vdst[0:31] with vsrc[32:63].
// With vdst = vsrc = v, the two results are:
//   r[0] = value the HIGH half held, broadcast to all 64 lanes
//   r[1] = value the LOW  half held, broadcast to all 64 lanes
// One VALU op replaces a ds_bpermute round-trip AND the cndmask selects.
typedef unsigned int uint2v __attribute__((ext_vector_type(2)));
__device__ __forceinline__ void swap_halves(float v, float& hiAll, float& loAll) {
    uint2v r = __builtin_amdgcn_permlane32_swap(__float_as_uint(v),
                                                __float_as_uint(v),
                                                false, false);
    hiAll = __uint_as_float(r[0]);
    loAll = __uint_as_float(r[1]);
}

// Broadcast lane k's value (k constant after unroll) -> SGPR, feeds v_fmac
// directly as the scalar operand. No LDS pipe, no ds latency.
__device__ __forceinline__ float bcast(float v, int k) {
    return __int_as_float(__builtin_amdgcn_readlane(__float_as_int(v), k));
}

// Load one 32-float weight row into registers, pre-scaled.
#define LOADROW(dst, base, row, sc)                                            \
    {                                                                          \
        const float4* W_ = reinterpret_cast<const float4*>((base) +            \
                                                    (size_t)(row) * HID);      \
        _Pragma("unroll")                                                      \
        for (int k4 = 0; k4 < 8; ++k4) {                                       \
            float4 v_ = W_[k4];                                                \
            dst[4 * k4 + 0] = v_.x * (sc);                                     \
            dst[4 * k4 + 1] = v_.y * (sc);                                     \
            dst[4 * k4 + 2] = v_.z * (sc);                                     \
            dst[4 * k4 + 3] = v_.w * (sc);                                     \
        }                                                                      \
    }

// Fused 3-layer LSTM, software-pipelined across waves.
// Block = 192 threads = 3 waves; wave w = layer w; blockIdx = batch element.
// At tick t, wave w processes step s = t - w.
// Own-layer h(t-1) stays IN REGISTERS (readlane broadcast); only the
// layer->layer+1 hand-off goes through a tiny double-buffered LDS ring.
// Lane l owns rows gA=l, gB=l+64 (torch order i,f,g,o):
//   lanes 0-31 (j=l):    i_j (accA), g_j (accB)
//   lanes 32-63 (j=l-32): f_j (accA), o_j (accB)
// Weights/biases pre-scaled by log2e (g rows by 2*log2e): activation is the
// uniform sigma(y)=rcp(1+exp2(-y)); tanh(g)=2*sigma(2g)-1.
// x block-slice staged in LDS once -> zero per-tick global loads.
__global__ __launch_bounds__(192, 2)
void lstm3_fused(const float* __restrict__ x,
                 const float* __restrict__ Wih0, const float* __restrict__ Whh0,
                 const float* __restrict__ bih0, const float* __restrict__ bhh0,
                 const float* __restrict__ Wih1, const float* __restrict__ Whh1,
                 const float* __restrict__ bih1, const float* __restrict__ bhh1,
                 const float* __restrict__ Wih2, const float* __restrict__ Whh2,
                 const float* __restrict__ bih2, const float* __restrict__ bhh2,
                 float* __restrict__ hseq)
{
    const int b = blockIdx.x;
    const int w = threadIdx.x >> 6;   // wave id == layer id, 0..2
    const int l = threadIdx.x & 63;
    const int j = l & 31;
    const bool lowHalf = (l < 32);
    const int gA = l;
    const int gB = l + 64;
    const float sA = LOG2E;
    const float sB = lowHalf ? (2.0f * LOG2E) : LOG2E;  // g rows get 2*log2e

    // x slice for this batch element: xl4[s] = x[s][b][0..3], xl1[s] = x[s][b][4]
    __shared__ float4 xl4[S_LEN];     // 16 KB
    __shared__ float  xl1[S_LEN];     //  4 KB
    // ring[parity][src_wave][unit]: wave0 writes slot0 (read by wave1),
    // wave1 writes slot1 (read by wave2). Wave2 -> global hseq only.
    __shared__ float ring[2][2][HID];

    for (int i = threadIdx.x; i < 2 * 2 * HID; i += 192)
        (&ring[0][0][0])[i] = 0.0f;
    {
        float* xf = reinterpret_cast<float*>(xl4);
        for (int idx = threadIdx.x; idx < S_LEN * 5; idx += 192) {
            const int s = idx / 5;
            const int c = idx - 5 * s;
            const float v = x[(size_t)s * (BATCH * 5) + b * 5 + c];
            if (c < 4) xf[s * 4 + c] = v;
            else       xl1[s] = v;
        }
    }

    const float* Wih = (w == 0) ? Wih0 : (w == 1) ? Wih1 : Wih2;
    const float* Whh = (w == 0) ? Whh0 : (w == 1) ? Whh1 : Whh2;
    const float* bih = (w == 0) ? bih0 : (w == 1) ? bih1 : bih2;
    const float* bhh = (w == 0) ? bhh0 : (w == 1) ? bhh1 : bhh2;

    // Recurrent weight rows in registers (all waves), pre-scaled
    float whA[HID], whB[HID];
    LOADROW(whA, Whh, gA, sA);
    LOADROW(whB, Whh, gB, sB);
    // Input weight rows: wave 0 has KIN=5, waves 1/2 have KIN=32.
    float wiA[HID], wiB[HID];
    float wxA[5], wxB[5];
    if (w == 0) {
#pragma unroll
        for (int k = 0; k < 5; ++k) {
            wxA[k] = Wih[gA * 5 + k] * sA;
            wxB[k] = Wih[gB * 5 + k] * sB;
        }
    } else {
        LOADROW(wiA, Wih, gA, sA);
        LOADROW(wiB, Wih, gB, sB);
    }
    const float biasA = (bih[gA] + bhh[gA]) * sA;
    const float biasB = (bih[gB] + bhh[gB]) * sB;

    float c = 0.0f;
    float h_own = 0.0f;   // own-layer h(t-1), unit j, identical in both halves

    __syncthreads();  // staging + ring init visible (one-time full barrier)

    for (int t = 0; t < S_LEN + 2; ++t) {
        const int s = t - w;
        const bool active = (s >= 0) && (s < S_LEN);
        const int p = t & 1;

        // ---- gate matvecs: acc = bias + Whh*h_own + Wih*input ----
        float aA0 = biasA, aA1 = 0.f, aA2 = 0.f, aA3 = 0.f;
        float aB0 = biasB, aB1 = 0.f, aB2 = 0.f, aB3 = 0.f;

        // own h via readlane broadcast (register-only, no LDS)
#pragma unroll
        for (int k4 = 0; k4 < HID / 4; ++k4) {
            const float h0 = bcast(h_own, 4 * k4 + 0);
            const float h1 = bcast(h_own, 4 * k4 + 1);
            const float h2 = bcast(h_own, 4 * k4 + 2);
            const float h3 = bcast(h_own, 4 * k4 + 3);
            aA0 += whA[4 * k4 + 0] * h0;
            aA1 += whA[4 * k4 + 1] * h1;
            aA2 += whA[4 * k4 + 2] * h2;
            aA3 += whA[4 * k4 + 3] * h3;
            aB0 += whB[4 * k4 + 0] * h0;
            aB1 += whB[4 * k4 + 1] * h1;
            aB2 += whB[4 * k4 + 2] * h2;
            aB3 += whB[4 * k4 + 3] * h3;
        }

        if (w == 0) {
            if (active) {   // wave-uniform branch
                const float4 xv = xl4[s];
                const float  x4 = xl1[s];
                aA0 += wxA[0] * xv.x; aB0 += wxB[0] * xv.x;
                aA1 += wxA[1] * xv.y; aB1 += wxB[1] * xv.y;
                aA2 += wxA[2] * xv.z; aB2 += wxB[2] * xv.z;
                aA3 += wxA[3] * xv.w; aB3 += wxB[3] * xv.w;
                aA0 += wxA[4] * x4;   aB0 += wxB[4] * x4;
            }
        } else {
            // input = previous layer's h from LDS ring (broadcast b128 reads)
            const float4* hin4 = reinterpret_cast<const float4*>(&ring[p][w - 1][0]);
#pragma unroll
            for (int k4 = 0; k4 < HID / 4; ++k4) {
                float4 hv = hin4[k4];
                aA0 += wiA[4 * k4 + 0] * hv.x;
                aA1 += wiA[4 * k4 + 1] * hv.y;
                aA2 += wiA[4 * k4 + 2] * hv.z;
                aA3 += wiA[4 * k4 + 3] * hv.w;
                aB0 += wiB[4 * k4 + 0] * hv.x;
                aB1 += wiB[4 * k4 + 1] * hv.y;
                aB2 += wiB[4 * k4 + 2] * hv.z;
                aB3 += wiB[4 * k4 + 3] * hv.w;
            }
        }
        const float accA = (aA0 + aA1) + (aA2 + aA3);
        const float accB = (aB0 + aB1) + (aB2 + aB3);

        // ---- half-exchange via permlane32_swap: all lanes get all 4 gates --
        float yf, yi, yo, yg;
        swap_halves(accA, yf, yi);   // accA: low half held i, high half held f
        swap_halves(accB, yo, yg);   // accB: low half held g, high half held o

        const float gi = fast_rcp(1.0f + fast_exp2(-yi));
        const float gf = fast_rcp(1.0f + fast_exp2(-yf));
        const float sg = fast_rcp(1.0f + fast_exp2(-yg));
        const float go = fast_rcp(1.0f + fast_exp2(-yo));
        const float gg = 2.0f * sg - 1.0f;      // tanh(g) = 2*sigma(2g) - 1

        const float c_new = gf * c + gi * gg;
        const float e  = fast_exp2(-2.0f * LOG2E * fabsf(c_new));
        const float tc = copysignf((1.0f - e) * fast_rcp(1.0f + e), c_new);
        const float h = go * tc;                // identical in both halves

        if (active) {
            c = c_new;
            h_own = h;                          // stays in registers
            if (w < 2) {
                if (lowHalf) ring[p ^ 1][w][j] = h;   // hand-off to layer w+1
            } else {
                if (lowHalf)
                    hseq[((size_t)s * BATCH + b) * HID + j] = h;  // never waited
            }
        }
        tick_barrier();   // lgkmcnt-only: global stores stream, no vmcnt drain
    }
}

// MLP head: per (s,b): y = relu(w3 . (W2 (W1 h + b1) + b2) + b3)
__global__ __launch_bounds__(256)
void mlp_kernel(const float* __restrict__ h, const float* __restrict__ w1,
                const float* __restrict__ b1, const float* __restrict__ w2,
                const float* __restrict__ b2, const float* __restrict__ w3,
                const float* __restrict__ b3, float* __restrict__ out)
{
    __shared__ float W1[HID * HID];
    __shared__ float W2[HID * HID];
    __shared__ float W3[HID];
    __shared__ float B1[HID];
    __shared__ float B2[HID];
    __shared__ float B3s;

    for (int i = threadIdx.x; i < HID * HID; i += blockDim.x) {
        W1[i] = w1[i];
        W2[i] = w2[i];
    }
    if (threadIdx.x < HID) {
        W3[threadIdx.x] = w3[threadIdx.x];
        B1[threadIdx.x] = b1[threadIdx.x];
        B2[threadIdx.x] = b2[threadIdx.x];
    }
    if (threadIdx.x == 0) B3s = b3[0];
    __syncthreads();

    const size_t e = (size_t)blockIdx.x * blockDim.x + threadIdx.x;  // (s*B+b)
    float hv[HID];
    const float4* hp = reinterpret_cast<const float4*>(h + e * HID);
#pragma unroll
    for (int k4 = 0; k4 < HID / 4; ++k4) {
        float4 v = hp[k4];
        hv[4 * k4 + 0] = v.x;
        hv[4 * k4 + 1] = v.y;
        hv[4 * k4 + 2] = v.z;
        hv[4 * k4 + 3] = v.w;
    }

    float y1[HID];
#pragma unroll
    for (int jj = 0; jj < HID; ++jj) {
        float acc = B1[jj];
#pragma unroll
        for (int k = 0; k < HID; ++k) acc += W1[jj * HID + k] * hv[k];
        y1[jj] = acc;
    }
    float y2[HID];
#pragma unroll
    for (int jj = 0; jj < HID; ++jj) {
        float acc = B2[jj];
#pragma unroll
        for (int k = 0; k < HID; ++k) acc += W2[jj * HID + k] * y1[k];
        y2[jj] = acc;
    }
    float acc3 = B3s;
#pragma unroll
    for (int k = 0; k < HID; ++k) acc3 += W3[k] * y2[k];
    out[e] = fmaxf(acc3, 0.0f);
}

extern "C" void kernel_launch(void* const* d_in, const int* in_sizes, int n_in,
                              void* d_out, int out_size, void* d_ws, size_t ws_size,
                              hipStream_t stream)
{
    const float* x    = (const float*)d_in[0];
    const float* Wih0 = (const float*)d_in[1];
    const float* Whh0 = (const float*)d_in[2];
    const float* bih0 = (const float*)d_in[3];
    const float* bhh0 = (const float*)d_in[4];
    const float* Wih1 = (const float*)d_in[5];
    const float* Whh1 = (const float*)d_in[6];
    const float* bih1 = (const float*)d_in[7];
    const float* bhh1 = (const float*)d_in[8];
    const float* Wih2 = (const float*)d_in[9];
    const float* Whh2 = (const float*)d_in[10];
    const float* bih2 = (const float*)d_in[11];
    const float* bhh2 = (const float*)d_in[12];
    const float* w1   = (const float*)d_in[13];
    const float* b1   = (const float*)d_in[14];
    const float* w2   = (const float*)d_in[15];
    const float* b2   = (const float*)d_in[16];
    const float* w3   = (const float*)d_in[17];
    const float* b3   = (const float*)d_in[18];

    // [S, BATCH, HID] fp32 buffer (64 MB) for layer-2 output
    float* hseq = (float*)d_ws;

    lstm3_fused<<<BATCH, 192, 0, stream>>>(x, Wih0, Whh0, bih0, bhh0,
                                           Wih1, Whh1, bih1, bhh1,
                                           Wih2, Whh2, bih2, bhh2, hseq);

    mlp_kernel<<<(S_LEN * BATCH) / 256, 256, 0, stream>>>(hseq, w1, b1, w2, b2, w3, b3,
                                                          (float*)d_out);
}